// Round 4
// baseline (1042.600 us; speedup 1.0000x reference)
//
#include <hip/hip_runtime.h>

#define N_NODES 10242
#define NNZ_E   71694
#define BT      32      // B*T
#define C_IN    16
#define K_S     20
#define C_OUT   32
#define F       512     // BT * C_IN
typedef unsigned short u16;
typedef unsigned int   u32;

#define SLICE_FLOATS ((size_t)N_NODES * 64)   // fp32 elems per slice
#define BUF_FLOATS   ((size_t)N_NODES * F)    // fp32 ring buffer (sliced layout [8][N][64])
#define BUF_BYTES    (BUF_FLOATS * 4)         // ~21 MB
#define PROJ_ELEMS   ((size_t)N_NODES * F)    // bf16 proj copy, layout [N][bt*16+c]
#define PROJ_BYTES   (PROJ_ELEMS * 2)         // ~10.5 MB

__device__ __forceinline__ float bf2f(u32 h) {
    union { u32 u; float f; } v; v.u = h << 16; return v.f;
}
__device__ __forceinline__ u16 f2bf(float f) {
    union { float f; u32 u; } v; v.f = f;
    u32 r = v.u + 0x7fffu + ((v.u >> 16) & 1u);   // RNE
    return (u16)(r >> 16);
}
__device__ __forceinline__ void unpack8(uint4 u, float* f) {
    f[0] = bf2f(u.x & 0xffffu); f[1] = bf2f(u.x >> 16);
    f[2] = bf2f(u.y & 0xffffu); f[3] = bf2f(u.y >> 16);
    f[4] = bf2f(u.z & 0xffffu); f[5] = bf2f(u.z >> 16);
    f[6] = bf2f(u.w & 0xffffu); f[7] = bf2f(u.w >> 16);
}

// ---------------- CSR build (deterministic) ----------------

__global__ void zero_kernel(int* p, int n) {
    int i = blockIdx.x * blockDim.x + threadIdx.x;
    if (i < n) p[i] = 0;
}

__global__ void count_kernel(const int* __restrict__ erow, int* cnt) {
    int e = blockIdx.x * blockDim.x + threadIdx.x;
    if (e < NNZ_E) atomicAdd(&cnt[erow[e]], 1);
}

__global__ void scan_kernel(const int* __restrict__ cnt, int* row_ptr, int* cursor) {
    const int T = 256;
    const int chunk = (N_NODES + T - 1) / T;  // 41
    __shared__ int part[T];
    int t = threadIdx.x;
    int base = t * chunk;
    int s = 0;
    for (int i = 0; i < chunk; ++i) {
        int idx = base + i;
        if (idx < N_NODES) s += cnt[idx];
    }
    part[t] = s;
    __syncthreads();
    for (int off = 1; off < T; off <<= 1) {
        int v = (t >= off) ? part[t - off] : 0;
        __syncthreads();
        part[t] += v;
        __syncthreads();
    }
    int run = (t == 0) ? 0 : part[t - 1];
    for (int i = 0; i < chunk; ++i) {
        int idx = base + i;
        if (idx < N_NODES) {
            row_ptr[idx] = run;
            cursor[idx]  = run;
            run += cnt[idx];
        }
    }
    if (base <= N_NODES && N_NODES < base + chunk) {
        row_ptr[N_NODES] = run;
    }
}

// scatter ORIGINAL EDGE INDEX (order nondeterministic here, fixed by sort below)
__global__ void scatter_kernel(const int* __restrict__ erow, int* cursor, int* __restrict__ eidx) {
    int e = blockIdx.x * blockDim.x + threadIdx.x;
    if (e < NNZ_E) {
        int p = atomicAdd(&cursor[erow[e]], 1);
        eidx[p] = e;
    }
}

// per-row insertion sort of edge indices -> deterministic order every launch
__global__ void sort_rows_kernel(const int* __restrict__ row_ptr, int* eidx) {
    int r = blockIdx.x * blockDim.x + threadIdx.x;
    if (r >= N_NODES) return;
    int s = row_ptr[r], e = row_ptr[r + 1];
    for (int i = s + 1; i < e; ++i) {
        int key = eidx[i];
        int j = i - 1;
        while (j >= s && eidx[j] > key) { eidx[j + 1] = eidx[j]; --j; }
        eidx[j + 1] = key;
    }
}

__global__ void fill_csr_kernel(const int* __restrict__ eidx,
                                const int* __restrict__ ecol, const float* __restrict__ eval,
                                int* __restrict__ ccol, float* __restrict__ cval) {
    int p = blockIdx.x * blockDim.x + threadIdx.x;
    if (p < NNZ_E) {
        int e = eidx[p];
        ccol[p] = ecol[e];
        cval[p] = eval[e];
    }
}

// Wt[k][c][cout] = W[cout][c*K_S + k]
__global__ void wt_kernel(const float* __restrict__ W, float* __restrict__ Wt) {
    int i = blockIdx.x * blockDim.x + threadIdx.x;  // 10240
    if (i < K_S * C_IN * C_OUT) {
        int cout = i & 31;
        int c    = (i >> 5) & 15;
        int k    = i >> 9;
        Wt[i] = W[cout * (C_IN * K_S) + c * K_S + k];
    }
}

// ---------------- transform: x -> T0 (fp32, sliced) + bf16 proj copy -------
// sliced layout: Ts[s][n][bt_local*16 + c], bt = s*4 + bt_local

__global__ __launch_bounds__(64) void transform_kernel(
        const float* __restrict__ x, float* __restrict__ T0, u16* __restrict__ proj0) {
    int s = blockIdx.x & 7;
    int n = blockIdx.x >> 3;
    int lane = threadIdx.x;               // = bt_local*16 + c
    int bt = s * 4 + (lane >> 4);
    int c  = lane & 15;
    float v = x[((size_t)bt * N_NODES + n) * C_IN + c];
    T0[(size_t)s * SLICE_FLOATS + (size_t)n * 64 + lane] = v;
    proj0[(size_t)n * F + s * 64 + lane] = f2bf(v);
}

// ---------------- Chebyshev step (fp32, XCD-sliced) + bf16 proj copy -------
// dst = alpha * L @ srcB + beta * srcA ; proj = bf16(dst)

__global__ __launch_bounds__(256) void spmm_step_kernel(
        const float* __restrict__ srcB, const float* __restrict__ srcA,
        float* __restrict__ dst, u16* __restrict__ projw,
        const int* __restrict__ row_ptr, const int* __restrict__ ccol,
        const float* __restrict__ cval, float alpha, float beta) {
    int s  = blockIdx.x & 7;              // slice -> XCD (blockIdx % 8 heuristic)
    int ng = blockIdx.x >> 3;             // group of 4 nodes
    int w  = threadIdx.x >> 6;
    int lane = threadIdx.x & 63;
    int n = ng * 4 + w;
    if (n >= N_NODES) return;             // wave-uniform

    const float* Bs = srcB + (size_t)s * SLICE_FLOATS;
    int start = row_ptr[n];
    int end   = row_ptr[n + 1];
    float acc0 = 0.f, acc1 = 0.f;
    int e = start;
    for (; e + 1 < end; e += 2) {
        int   c0 = ccol[e],  c1 = ccol[e + 1];
        float v0 = cval[e],  v1 = cval[e + 1];
        acc0 += v0 * Bs[(size_t)c0 * 64 + lane];
        acc1 += v1 * Bs[(size_t)c1 * 64 + lane];
    }
    if (e < end) acc0 += cval[e] * Bs[(size_t)ccol[e] * 64 + lane];

    size_t off = (size_t)s * SLICE_FLOATS + (size_t)n * 64 + lane;
    float y = alpha * (acc0 + acc1) + beta * srcA[off];
    dst[off] = y;
    projw[(size_t)n * F + s * 64 + lane] = f2bf(y);   // 128 B contiguous per wave
}

// ---------------- projection over a chunk of k values (bf16 in, fp32 out) --

__global__ __launch_bounds__(256) void proj_kernel(
        const u16* __restrict__ projbase, int Rbf, int k0, int kcnt,
        const float* __restrict__ Wt, float* __restrict__ out, int accumulate) {
    int g = blockIdx.x * 256 + threadIdx.x;   // over N*BT
    if (g >= N_NODES * BT) return;
    int bt = g & 31;
    int n  = g >> 5;

    float acc[C_OUT];
    #pragma unroll
    for (int co = 0; co < C_OUT; ++co) acc[co] = 0.f;

    for (int j = 0; j < kcnt; ++j) {
        int k = k0 + j;
        const u16* Trow = projbase + (size_t)(k % Rbf) * PROJ_ELEMS
                        + (size_t)n * F + bt * C_IN;
        uint4 u0 = ((const uint4*)Trow)[0];
        uint4 u1 = ((const uint4*)Trow)[1];
        float yv[C_IN];
        unpack8(u0, yv); unpack8(u1, yv + 8);
        const float* wk = Wt + (size_t)k * C_IN * C_OUT;
        #pragma unroll
        for (int c = 0; c < C_IN; ++c) {
            #pragma unroll
            for (int co = 0; co < C_OUT; ++co)
                acc[co] += yv[c] * wk[c * C_OUT + co];
        }
    }

    float* op = out + ((size_t)bt * N_NODES + n) * C_OUT;
    if (accumulate) {
        #pragma unroll
        for (int co = 0; co < C_OUT; ++co) acc[co] += op[co];
    }
    #pragma unroll
    for (int qq = 0; qq < 8; ++qq)
        *(float4*)(op + 4 * qq) = *(float4*)(acc + 4 * qq);
}

// ---------------- host launch ----------------

extern "C" void kernel_launch(void* const* d_in, const int* in_sizes, int n_in,
                              void* d_out, int out_size, void* d_ws, size_t ws_size,
                              hipStream_t stream) {
    const float* x    = (const float*)d_in[0];
    const int*   erow = (const int*)  d_in[1];
    const int*   ecol = (const int*)  d_in[2];
    const float* eval = (const float*)d_in[3];
    const float* W    = (const float*)d_in[4];
    float* out = (float*)d_out;

    char* ws = (char*)d_ws;
    size_t o = 0;
    auto alloc = [&](size_t bytes) -> char* {
        o = (o + 511) & ~(size_t)511;
        char* r = ws + o;
        o += bytes;
        return r;
    };
    int*   cnt     = (int*)  alloc((size_t)N_NODES * 4);
    int*   row_ptr = (int*)  alloc((size_t)(N_NODES + 1) * 4);
    int*   cursor  = (int*)  alloc((size_t)N_NODES * 4);
    int*   eidx    = (int*)  alloc((size_t)NNZ_E * 4);
    int*   ccol    = (int*)  alloc((size_t)NNZ_E * 4);
    float* cval    = (float*)alloc((size_t)NNZ_E * 4);
    float* Wt      = (float*)alloc((size_t)K_S * C_IN * C_OUT * 4);

    // fp32 recurrence ring: 3 buffers (sliced layout)
    float* fbase = (float*)alloc(3 * BUF_BYTES);
    auto buf = [&](int k) -> float* { return fbase + (size_t)(k % 3) * BUF_FLOATS; };

    // bf16 proj ring: as many slots as workspace allows (proven ws >= ~212 MB -> >= 14)
    o = (o + 511) & ~(size_t)511;
    size_t remain = (ws_size > o) ? (ws_size - o) : 0;
    int Rbf = (int)(remain / PROJ_BYTES);
    if (Rbf > K_S) Rbf = K_S;
    if (Rbf < 1)  Rbf = 1;
    u16* projbase = (u16*)alloc((size_t)Rbf * PROJ_BYTES);
    auto projslot = [&](int k) -> u16* { return projbase + (size_t)(k % Rbf) * PROJ_ELEMS; };

    // CSR build (deterministic) + weight transpose
    zero_kernel<<<(N_NODES + 255) / 256, 256, 0, stream>>>(cnt, N_NODES);
    count_kernel<<<(NNZ_E + 255) / 256, 256, 0, stream>>>(erow, cnt);
    scan_kernel<<<1, 256, 0, stream>>>(cnt, row_ptr, cursor);
    scatter_kernel<<<(NNZ_E + 255) / 256, 256, 0, stream>>>(erow, cursor, eidx);
    sort_rows_kernel<<<(N_NODES + 255) / 256, 256, 0, stream>>>(row_ptr, eidx);
    fill_csr_kernel<<<(NNZ_E + 255) / 256, 256, 0, stream>>>(eidx, ecol, eval, ccol, cval);
    wt_kernel<<<(K_S * C_IN * C_OUT + 255) / 256, 256, 0, stream>>>(W, Wt);

    const int proj_blocks = (N_NODES * BT + 255) / 256;
    int c0 = 0;
    auto maybe_pass = [&](int k_done) {
        int target = K_S - c0;
        if (target > Rbf) target = Rbf;
        if (target > 0 && (k_done - c0 + 1) == target) {
            proj_kernel<<<proj_blocks, 256, 0, stream>>>(
                projbase, Rbf, c0, target, Wt, out, (c0 > 0) ? 1 : 0);
            c0 += target;
        }
    };

    // T0
    transform_kernel<<<N_NODES * 8, 64, 0, stream>>>(x, buf(0), projslot(0));
    maybe_pass(0);

    // T1 = L T0 ; Tk = 2 L T_{k-1} - T_{k-2}
    const int spmm_blocks = ((N_NODES + 3) / 4) * 8;
    for (int k = 1; k < K_S; ++k) {
        const float* srcB = buf(k - 1);
        const float* srcA = (k >= 2) ? buf(k - 2) : buf(k - 1);  // beta=0 when k==1
        float alpha = (k == 1) ? 1.f : 2.f;
        float beta  = (k == 1) ? 0.f : -1.f;
        spmm_step_kernel<<<spmm_blocks, 256, 0, stream>>>(
            srcB, srcA, buf(k), projslot(k), row_ptr, ccol, cval, alpha, beta);
        maybe_pass(k);
    }
}